// Round 10
// baseline (562.998 us; speedup 1.0000x reference)
//
#include <hip/hip_runtime.h>
#include <hip/hip_bf16.h>

// GNN: node_proj + edge scatter_mean/proj -> concat -> GAT(512->4x64) -> ELU
//      -> GAT(256->4x64) -> ELU -> out_proj. ALL tensors float32 (per ref).
// R16: GEMM restructured to BARRIER-FREE main loop. Each block owns a 64-col
//      quarter (= one head) and stages its ENTIRE B panel (all K) to LDS
//      once: K=256 -> 64KB (2 blocks/CU), K=160 -> 40KB. One barrier after
//      the stage; the k-loop is then pure {A-load, ds_read, MFMA} with no
//      vmcnt(0) drains -- the mechanism that defeated R10/R12/R15 pipelining
//      (every __syncthreads re-drained in-flight loads) is gone. Blocks =
//      128 rows x 64 cols, wave = 32 rows (acc[2][4]), grid (391,4);
//      col-quarter == head so fused att-dots store direct at gh=blockIdx.y.
//      Agg untouched: ~3.0 TB/s fabric gather ceiling (6th measurement).

#define HEADS 4

typedef __attribute__((ext_vector_type(8))) _Float16 f16x8;
typedef __attribute__((ext_vector_type(4))) float f32x4;
typedef __attribute__((ext_vector_type(4))) unsigned short u16x4;
typedef __attribute__((ext_vector_type(8))) unsigned short u16x8;

__device__ __forceinline__ unsigned short f2h(float v) {
    _Float16 h = (_Float16)v;                 // v_cvt_f16_f32, RN
    return __builtin_bit_cast(unsigned short, h);
}
__device__ __forceinline__ float h2f(unsigned short u) {
    return (float)__builtin_bit_cast(_Float16, u);
}
// fp16 hi/lo split: h + l reproduces v to ~22 mantissa bits
__device__ __forceinline__ void split_hilo16(float v, unsigned short& h, unsigned short& l) {
    h = f2h(v);
    l = f2h(v - h2f(h));
}
// async global->LDS, 16B per lane; LDS dest is wave-uniform base + lane*16
__device__ __forceinline__ void gl2lds16(const unsigned short* g, unsigned short* l) {
    __builtin_amdgcn_global_load_lds(
        (const __attribute__((address_space(1))) unsigned int*)g,
        (__attribute__((address_space(3))) unsigned int*)l,
        16, 0, 0);
}

// ============================ CSR construction =============================

__global__ __launch_bounds__(256) void count_kernel(
    const int* __restrict__ dst, int* __restrict__ cnt, int E)
{
    int e = blockIdx.x * 256 + threadIdx.x;
    if (e < E) atomicAdd(&cnt[dst[e]], 1);
}

__global__ __launch_bounds__(256) void scan1_kernel(
    const int* __restrict__ cnt, int* __restrict__ chunk_sum, int N)
{
    __shared__ int sd[256];
    int t = threadIdx.x;
    int n = blockIdx.x * 256 + t;
    sd[t] = (n < N) ? (cnt[n] + 1) : 0;
    __syncthreads();
    for (int o = 128; o > 0; o >>= 1) {
        if (t < o) sd[t] += sd[t + o];
        __syncthreads();
    }
    if (t == 0) chunk_sum[blockIdx.x] = sd[0];
}

// 1-block 256-thread scan over chunk sums
__global__ __launch_bounds__(256) void scan2_kernel(
    const int* __restrict__ chunk_sum, int* __restrict__ chunk_off, int nchunk)
{
    __shared__ int sd[256];
    __shared__ int carry;
    int t = threadIdx.x;
    if (t == 0) carry = 0;
    __syncthreads();
    for (int b = 0; b < nchunk; b += 256) {
        int i = b + t;
        int v = (i < nchunk) ? chunk_sum[i] : 0;
        sd[t] = v;
        __syncthreads();
        for (int o = 1; o < 256; o <<= 1) {
            int x = (t >= o) ? sd[t - o] : 0;
            __syncthreads();
            sd[t] += x;
            __syncthreads();
        }
        if (i < nchunk) chunk_off[i] = carry + sd[t] - v;
        __syncthreads();
        if (t == 0) carry += sd[255];
        __syncthreads();
    }
}

__global__ __launch_bounds__(256) void scan3_kernel(
    const int* __restrict__ cnt, const int* __restrict__ chunk_off,
    int* __restrict__ rowptr, int* __restrict__ fillptr,
    int* __restrict__ col, int* __restrict__ eid, int N)
{
    __shared__ int sd[256];
    int t = threadIdx.x;
    int n = blockIdx.x * 256 + t;
    int v = (n < N) ? (cnt[n] + 1) : 0;
    sd[t] = v;
    __syncthreads();
    for (int o = 1; o < 256; o <<= 1) {
        int x = (t >= o) ? sd[t - o] : 0;
        __syncthreads();
        sd[t] += x;
        __syncthreads();
    }
    if (n < N) {
        int incl = sd[t];
        int r = chunk_off[blockIdx.x] + incl - v;
        rowptr[n] = r;
        col[r] = n;        // self loop, first entry
        eid[r] = -1;
        fillptr[n] = r + 1;
        if (n == N - 1) rowptr[N] = chunk_off[blockIdx.x] + incl;
    }
}

__global__ __launch_bounds__(256) void fill_kernel(
    const int* __restrict__ src, const int* __restrict__ dst,
    int* __restrict__ fillptr, int* __restrict__ col, int* __restrict__ eid, int E)
{
    int e = blockIdx.x * 256 + threadIdx.x;
    if (e >= E) return;
    int d = dst[e];
    int p = atomicAdd(&fillptr[d], 1);
    col[p] = src[e];
    eid[p] = e;
}

// ====== edge_attr scatter-mean via CSR -> compact fp16 nef [N x 32] ========
// cols 0..15 = mean(edge_attr), 16..31 = zero (K padding for the GEMM).
__global__ __launch_bounds__(256) void nef_csr_kernel(
    const float* __restrict__ ea, const int* __restrict__ rowptr,
    const int* __restrict__ eid,
    unsigned short* __restrict__ nefF, int N)
{
    int n = blockIdx.x * 4 + (threadIdx.x >> 6);
    if (n >= N) return;
    int t = threadIdx.x & 63;
    int f = t & 15, g = t >> 4;
    int base = rowptr[n], end = rowptr[n + 1];
    int deg = end - base - 1;
    float acc = 0.0f;
    for (int j = base + 1 + g; j < end; j += 4) {
        int e = eid[j];
        acc += ea[(size_t)e * 16 + f];
    }
    acc += __shfl_down(acc, 32, 64);
    acc += __shfl_down(acc, 16, 64);
    if (t < 16) {
        float v = acc / fmaxf((float)deg, 1.0f);
        nefF[(size_t)n * 32 + t] = f2h(v);
    } else if (t < 32) {
        nefF[(size_t)n * 32 + t] = 0;
    }
}

// ====== compose front-end weights (f32, exact):
// Wc rows 0..127 = Wnp @ Wg1[0:256,:], rows 128..143 = Wep @ Wg1[256:512,:],
// c1[j] = bnp @ Wg1[0:256,j] + bep @ Wg1[256:512,j].
__global__ __launch_bounds__(256) void compose_w1_kernel(
    const float* __restrict__ Wnp, const float* __restrict__ Wep,
    const float* __restrict__ bnp, const float* __restrict__ bep,
    const float* __restrict__ Wg1,
    float* __restrict__ Wc, float* __restrict__ c1)
{
    int idx = blockIdx.x * 256 + threadIdx.x;
    if (idx >= 145 * 256) return;
    int i = idx >> 8, j = idx & 255;
    float s = 0.0f;
    if (i < 128) {
        for (int k = 0; k < 256; k++) s += Wnp[i * 256 + k] * Wg1[(size_t)k * 256 + j];
        Wc[i * 256 + j] = s;
    } else if (i < 144) {
        int ii = i - 128;
        for (int k = 0; k < 256; k++) s += Wep[ii * 256 + k] * Wg1[(size_t)(256 + k) * 256 + j];
        Wc[i * 256 + j] = s;
    } else {
        for (int k = 0; k < 256; k++)
            s += bnp[k] * Wg1[(size_t)k * 256 + j] + bep[k] * Wg1[(size_t)(256 + k) * 256 + j];
        c1[j] = s;
    }
}

// ==== pack 3 weight matrices [K x 256] -> B-fragment order, fp16 hi/lo ====
__device__ __forceinline__ void pack_one(
    const float* __restrict__ W, int K, int KP, int idx,
    unsigned short* __restrict__ Ph, unsigned short* __restrict__ Pl)
{
    int tile = idx >> 9, w = idx & 511, lane = w >> 3, j = w & 7;
    int nk = KP >> 5;
    int ctile = tile / nk, t = tile % nk;
    int k = t * 32 + ((lane >> 4) << 3) + j;
    int n = (ctile << 4) + (lane & 15);
    float v = (k < K) ? W[(size_t)k * 256 + n] : 0.0f;
    unsigned short h, l;
    split_hilo16(v, h, l);
    Ph[idx] = h;
    Pl[idx] = l;
}

__global__ __launch_bounds__(256) void pack3_w_kernel(
    const float* __restrict__ Wc,  unsigned short* __restrict__ PcH,  unsigned short* __restrict__ PcL,
    const float* __restrict__ Wg2, unsigned short* __restrict__ Pg2H, unsigned short* __restrict__ Pg2L,
    const float* __restrict__ Wo,  unsigned short* __restrict__ PoH,  unsigned short* __restrict__ PoL)
{
    const int S0 = 160 * 256;            // Wc: K=144, KP=160
    const int S1 = S0 + 256 * 256;       // Wg2
    const int S2 = S1 + 256 * 256;       // Wo
    int idx = blockIdx.x * 256 + threadIdx.x;
    if (idx < S0) {
        pack_one(Wc, 144, 160, idx, PcH, PcL);
    } else if (idx < S1) {
        pack_one(Wg2, 256, 256, idx - S0, Pg2H, Pg2L);
    } else if (idx < S2) {
        pack_one(Wo, 256, 256, idx - S1, PoH, PoL);
    }
}

// ===================== MFMA fp16 GEMM (barrier-free k-loop) ================
// C[N x 256] = A[N x KP] @ W[KP x 256] (+bias). Block: 128 rows x 64 cols
// (grid (ceil(N/128), 4)); col-quarter == head. 4 waves; wave = 32 rows
// (2 fragments), 4 col-tiles. The FULL B panel (4 ctiles x all K, fp16
// hi/lo) is staged to LDS once (wave w stages ctile w), ONE barrier, then
// the k-loop runs with no barriers -- A loads & ds_reads pipeline freely.
// AMODE: 0 = fp16 hilo A (3 MFMAs/frag), 1 = fp16 single (2 MFMAs),
// 3 = GEMM1-direct (ksteps 0..KS-2 from f32 Af32 [N x 128], cvt in-reg;
// last kstep from compact nef fp16 [N x 32]). OMODE: 0 = f32, 1 = fp16
// hilo, 2 = fp16. FUSE_ATT: per-row head-dot of (acc+bias), gh = blockIdx.y.
template <int KSTEPS, int AMODE, int OMODE, bool FUSE_ATT>
__global__ __launch_bounds__(256, 2) void mfma_gemm_kernel(
    const unsigned short* __restrict__ Ah, const unsigned short* __restrict__ Al,
    const float* __restrict__ Af32,
    int lda,
    const unsigned short* __restrict__ Ph, const unsigned short* __restrict__ Pl,
    const float* __restrict__ bias,
    float* __restrict__ Cf,
    unsigned short* __restrict__ Ch, unsigned short* __restrict__ Cl,
    int ldc, int col_off, int Nrows,
    const float* __restrict__ att_src, const float* __restrict__ att_dst,
    float* __restrict__ a_srcO, float* __restrict__ a_dstO)
{
    __shared__ unsigned short ldsB[2][4][KSTEPS * 512];   // [hi/lo][ctile][elem]
    int tid = threadIdx.x;
    int wave = tid >> 6, lane = tid & 63;
    int quad = lane >> 4, m16 = lane & 15;
    int rowblk = blockIdx.x, cq = blockIdx.y;             // col-quarter = head
    int ctile0 = cq * 4;

    int row0 = rowblk * 128 + wave * 32 + m16;
    int row1 = row0 + 16;
    bool ok0 = row0 < Nrows, ok1 = row1 < Nrows;

    // ---- stage FULL B panel once: wave w stages ctile w (hi+lo, all K) ----
    {
        int c = wave;                                     // 0..3
        #pragma unroll
        for (int t = 0; t < KSTEPS; t++) {
            size_t gb = ((size_t)((ctile0 + c) * KSTEPS + t)) * 512 + lane * 8;
            gl2lds16(Ph + gb, &ldsB[0][c][t * 512]);
            gl2lds16(Pl + gb, &ldsB[1][c][t * 512]);
        }
    }

    f32x4 acc[2][4] = {};
    __syncthreads();                                      // the ONLY barrier

    #pragma unroll
    for (int t = 0; t < KSTEPS; t++) {
        // A fragments for this k-step (no barriers below -> free pipelining)
        f16x8 a0 = {}, a1 = {}, al0 = {}, al1 = {};
        if (AMODE == 3) {
            if (t < KSTEPS - 1) {
                if (ok0) {
                    const float* p = Af32 + (size_t)row0 * 128 + t * 32 + quad * 8;
                    f32x4 x = *(const f32x4*)p, y = *(const f32x4*)(p + 4);
                    #pragma unroll
                    for (int i = 0; i < 4; i++) {
                        ((_Float16*)&a0)[i] = (_Float16)x[i];
                        ((_Float16*)&a0)[4 + i] = (_Float16)y[i];
                    }
                }
                if (ok1) {
                    const float* p = Af32 + (size_t)row1 * 128 + t * 32 + quad * 8;
                    f32x4 x = *(const f32x4*)p, y = *(const f32x4*)(p + 4);
                    #pragma unroll
                    for (int i = 0; i < 4; i++) {
                        ((_Float16*)&a1)[i] = (_Float16)x[i];
                        ((_Float16*)&a1)[4 + i] = (_Float16)y[i];
                    }
                }
            } else {
                if (ok0) a0 = __builtin_bit_cast(f16x8, *(const u16x8*)(Ah + (size_t)row0 * 32 + quad * 8));
                if (ok1) a1 = __builtin_bit_cast(f16x8, *(const u16x8*)(Ah + (size_t)row1 * 32 + quad * 8));
            }
        } else {
            int k = t * 32 + quad * 8;
            if (ok0) a0 = __builtin_bit_cast(f16x8, *(const u16x8*)(Ah + (size_t)row0 * lda + k));
            if (ok1) a1 = __builtin_bit_cast(f16x8, *(const u16x8*)(Ah + (size_t)row1 * lda + k));
            if (AMODE == 0) {
                if (ok0) al0 = __builtin_bit_cast(f16x8, *(const u16x8*)(Al + (size_t)row0 * lda + k));
                if (ok1) al1 = __builtin_bit_cast(f16x8, *(const u16x8*)(Al + (size_t)row1 * lda + k));
            }
        }

        #pragma unroll
        for (int c = 0; c < 4; c++) {
            f16x8 b_h = __builtin_bit_cast(f16x8, *(const u16x8*)&ldsB[0][c][t * 512 + lane * 8]);
            f16x8 b_l = __builtin_bit_cast(f16x8, *(const u16x8*)&ldsB[1][c][t * 512 + lane * 8]);
            acc[0][c] = __builtin_amdgcn_mfma_f32_16x16x32_f16(a0, b_h, acc[0][c], 0, 0, 0);
            if (AMODE == 0)
                acc[0][c] = __builtin_amdgcn_mfma_f32_16x16x32_f16(al0, b_h, acc[0][c], 0, 0, 0);
            acc[0][c] = __builtin_amdgcn_mfma_f32_16x16x32_f16(a0, b_l, acc[0][c], 0, 0, 0);
            acc[1][c] = __builtin_amdgcn_mfma_f32_16x16x32_f16(a1, b_h, acc[1][c], 0, 0, 0);
            if (AMODE == 0)
                acc[1][c] = __builtin_amdgcn_mfma_f32_16x16x32_f16(al1, b_h, acc[1][c], 0, 0, 0);
            acc[1][c] = __builtin_amdgcn_mfma_f32_16x16x32_f16(a1, b_l, acc[1][c], 0, 0, 0);
        }
    }

    // epilogue: D[row = quad*4 + r][col = m16] within each 16x16 tile
    #pragma unroll
    for (int f = 0; f < 2; f++) {
        #pragma unroll
        for (int c = 0; c < 4; c++) {
            int ocol = (ctile0 + c) * 16 + m16;
            float bv = bias ? bias[ocol] : 0.0f;
            #pragma unroll
            for (int r = 0; r < 4; r++) {
                int orow = rowblk * 128 + wave * 32 + f * 16 + quad * 4 + r;
                if (orow >= Nrows) continue;
                float v = acc[f][c][r] + bv;
                size_t oidx = (size_t)orow * ldc + col_off + ocol;
                if (OMODE == 1) {
                    unsigned short h, l;
                    split_hilo16(v, h, l);
                    Ch[oidx] = h;
                    Cl[oidx] = l;
                } else if (OMODE == 2) {
                    Ch[oidx] = f2h(v);
                } else {
                    Cf[oidx] = v;
                }
            }
        }
    }

    if (FUSE_ATT) {
        #pragma unroll
        for (int f = 0; f < 2; f++) {
            float ps[4] = {}, pd[4] = {};
            #pragma unroll
            for (int c = 0; c < 4; c++) {
                int ocol = (ctile0 + c) * 16 + m16;
                float bv = bias ? bias[ocol] : 0.0f;
                float asv = att_src[ocol];
                float adv = att_dst[ocol];
                #pragma unroll
                for (int r = 0; r < 4; r++) {
                    float v = acc[f][c][r] + bv;
                    ps[r] += v * asv;
                    pd[r] += v * adv;
                }
            }
            #pragma unroll
            for (int r = 0; r < 4; r++) {
                float s = ps[r], d = pd[r];
                #pragma unroll
                for (int o = 8; o > 0; o >>= 1) {
                    s += __shfl_down(s, o, 64);
                    d += __shfl_down(d, o, 64);
                }
                if (m16 == 0) {
                    int orow = rowblk * 128 + wave * 32 + f * 16 + quad * 4 + r;
                    if (orow < Nrows) {
                        a_srcO[orow * 4 + cq] = s;
                        a_dstO[orow * 4 + cq] = d;
                    }
                }
            }
        }
    }
}

// ===== CSR aggregation: wave-per-node; fused weight phase + weighted sum ===
// 4 nodes per 256-thread block; wave w owns node blockIdx*4+w.
// Phase 1 (fast path, deg<=128): lane-per-edge computes all 4 head weights
// into wave-private LDS + shuffle-reduced denominator (producer wave ==
// consumer wave, no barrier). Slow path (deg>128, ~never): inline weights.
// Phase 2: each lane covers 4 consecutive cols; masked unroll-4 gather.
// OUTF16: true -> single fp16 store (x3); false -> fp16 hilo (x4).
template <bool OUTF16>
__global__ __launch_bounds__(256) void gat_agg_csr_kernel(
    const unsigned short* __restrict__ xh,      // fp16 [N x 256]
    const int* __restrict__ rowptr, const int* __restrict__ col,
    const float* __restrict__ a_src, const float* __restrict__ a_dst,
    const float* __restrict__ bias,
    unsigned short* __restrict__ outA, unsigned short* __restrict__ outB, int N)
{
    __shared__ float wlds[4][128][HEADS];       // 8 KB, wave-private rows
    int t = threadIdx.x;
    int wv = t >> 6;
    int n = blockIdx.x * 4 + wv;
    if (n >= N) return;
    int c = t & 63;
    int h = c >> 4;
    int base = rowptr[n], end = rowptr[n + 1];
    int deg = end - base;                       // >= 1 (self loop)
    int e1 = end - 1;
    float4 ad = *(const float4*)&a_dst[n * 4];
    float adh = (h == 0) ? ad.x : (h == 1) ? ad.y : (h == 2) ? ad.z : ad.w;
    const unsigned short* xcol = xh + (c << 2);

    float4 acc = {0.0f, 0.0f, 0.0f, 0.0f};
    float den = 0.0f;

    if (deg <= 128) {
        // ---- phase 1: weights into LDS (lane-per-edge) + denominator ----
        float4 ds = {0.0f, 0.0f, 0.0f, 0.0f};
        for (int j = base + c; j < end; j += 64) {
            int s = col[j];
            float4 as4 = *(const float4*)&a_src[s * 4];
            float l0 = as4.x + ad.x, l1 = as4.y + ad.y;
            float l2 = as4.z + ad.z, l3 = as4.w + ad.w;
            l0 = fmaxf(l0, 0.2f * l0);
            l1 = fmaxf(l1, 0.2f * l1);
            l2 = fmaxf(l2, 0.2f * l2);
            l3 = fmaxf(l3, 0.2f * l3);
            float4 wv4 = {__expf(l0), __expf(l1), __expf(l2), __expf(l3)};
            *(float4*)&wlds[wv][j - base][0] = wv4;
            ds.x += wv4.x; ds.y += wv4.y; ds.z += wv4.z; ds.w += wv4.w;
        }
        #pragma unroll
        for (int o = 32; o > 0; o >>= 1) {
            ds.x += __shfl_down(ds.x, o, 64);
            ds.y += __shfl_down(ds.y, o, 64);
            ds.z += __shfl_down(ds.z, o, 64);
            ds.w += __shfl_down(ds.w, o, 64);
        }
        float d0 = __shfl(ds.x, 0, 64);
        float d1 = __shfl(ds.y, 0, 64);
        float d2 = __shfl(ds.z, 0, 64);
        float d3 = __shfl(ds.w, 0, 64);
        den = (h == 0) ? d0 : (h == 1) ? d1 : (h == 2) ? d2 : d3;

        // ---- phase 2: gather-accumulate, weights broadcast from LDS ----
        for (int j = base; j < end; j += 4) {
            int j1 = j + 1 < e1 ? j + 1 : e1;
            int j2 = j + 2 < e1 ? j + 2 : e1;
            int j3 = j + 3 < e1 ? j + 3 : e1;
            int s0 = col[j], s1 = col[j1], s2 = col[j2], s3 = col[j3];
            float w0 = wlds[wv][j - base][h];
            float w1 = (j + 1 < end) ? wlds[wv][j1 - base][h] : 0.0f;
            float w2 = (j + 2 < end) ? wlds[wv][j2 - base][h] : 0.0f;
            float w3 = (j + 3 < end) ? wlds[wv][j3 - base][h] : 0.0f;
            u16x4 x0 = *(const u16x4*)(xcol + (size_t)s0 * 256);
            u16x4 x1 = *(const u16x4*)(xcol + (size_t)s1 * 256);
            u16x4 x2 = *(const u16x4*)(xcol + (size_t)s2 * 256);
            u16x4 x3 = *(const u16x4*)(xcol + (size_t)s3 * 256);
            acc.x += w0 * h2f(x0[0]) + w1 * h2f(x1[0]) + w2 * h2f(x2[0]) + w3 * h2f(x3[0]);
            acc.y += w0 * h2f(x0[1]) + w1 * h2f(x1[1]) + w2 * h2f(x2[1]) + w3 * h2f(x3[1]);
            acc.z += w0 * h2f(x0[2]) + w1 * h2f(x1[2]) + w2 * h2f(x2[2]) + w3 * h2f(x3[2]);
            acc.w += w0 * h2f(x0[3]) + w1 * h2f(x1[3]) + w2 * h2f(x2[3]) + w3 * h2f(x3[3]);
        }
    } else {
        // ---- slow path (deg > 128, practically never): inline weights ----
        for (int j = base; j < end; j += 4) {
            int j1 = j + 1 < e1 ? j + 1 : e1;
            int j2 = j + 2 < e1 ? j + 2 : e1;
            int j3 = j + 3 < e1 ? j + 3 : e1;
            int s0 = col[j], s1 = col[j1], s2 = col[j2], s3 = col[j3];
            float l0 = a_src[s0 * 4 + h] + adh;
            float l1 = a_src[s1 * 4 + h] + adh;
            float l2 = a_src[s2 * 4 + h] + adh;
            float l3 = a_src[s3 * 4 + h] + adh;
            l0 = fmaxf(l0, 0.2f * l0);
            l1 = fmaxf(l1, 0.2f * l1);
            l2 = fmaxf(l2, 0.2f * l2);
            l3 = fmaxf(l3, 0.2f * l3);
            float w0 = __expf(l0);
            float w1 = (j + 1 < end) ? __expf(l1) : 0.0f;
            float w2 = (j + 2 < end) ? __expf(l2) : 0.0f;
            float w3 = (j + 3 < end) ? __expf(l3) : 0.0f;
            u16x4 x0 = *(const u16x4*)(xcol + (size_t)s0 * 256);
            u16x4 x1 = *(const u16x4*)(xcol + (size_t)s1 * 256);
            u16x4 x2 = *(const u16x4*)(xcol + (size_t)s2 * 256);
            u16x4 x3 = *(const u16x4*)(xcol + (size_t)s3 * 256);
            den += (w0 + w1) + (w2 + w3);
            acc.x += w0 * h2f(x0[0]) + w1 * h2f(x1[0]) + w2 * h2f(x2[0]) + w3 * h2f(x3[0]);
            acc.y += w0 * h2f(x0[1]) + w1 * h2f(x1[1]) + w2 * h2f(x2[1]) + w3 * h2f(x3[1]);
            acc.z += w0 * h2f(x0[2]) + w1 * h2f(x1[2]) + w2 * h2f(x2[2]) + w3 * h2f(x3[2]);
            acc.w += w0 * h2f(x0[3]) + w1 * h2f(x1[3]) + w2 * h2f(x2[3]) + w3 * h2f(x3[3]);
        }
    }

    float inv = 1.0f / den;
    float4 bv = *(const float4*)(bias + (c << 2));
    float o0 = acc.x * inv + bv.x;
    float o1 = acc.y * inv + bv.y;
    float o2 = acc.z * inv + bv.z;
    float o3 = acc.w * inv + bv.w;
    o0 = (o0 > 0.0f) ? o0 : (__expf(o0) - 1.0f);
    o1 = (o1 > 0.0f) ? o1 : (__expf(o1) - 1.0f);
    o2 = (o2 > 0.0f) ? o2 : (__expf(o2) - 1.0f);
    o3 = (o3 > 0.0f) ? o3 : (__expf(o3) - 1.0f);
    if (OUTF16) {
        u16x4 H;
        H[0] = f2h(o0); H[1] = f2h(o1); H[2] = f2h(o2); H[3] = f2h(o3);
        *(u16x4*)(&outA[(size_t)n * 256 + (c << 2)]) = H;
    } else {
        u16x4 H, L;
        split_hilo16(o0, ((unsigned short*)&H)[0], ((unsigned short*)&L)[0]);
        split_hilo16(o1, ((unsigned short*)&H)[1], ((unsigned short*)&L)[1]);
        split_hilo16(o2, ((unsigned short*)&H)[2], ((unsigned short*)&L)[2]);
        split_hilo16(o3, ((unsigned short*)&H)[3], ((unsigned short*)&L)[3]);
        *(u16x4*)(&outA[(size_t)n * 256 + (c << 2)]) = H;
        *(u16x4*)(&outB[(size_t)n * 256 + (c << 2)]) = L;
    }
}

// ===========================================================================

extern "C" void kernel_launch(void* const* d_in, const int* in_sizes, int n_in,
                              void* d_out, int out_size, void* d_ws, size_t ws_size,
                              hipStream_t stream)
{
    const float* node_feats = (const float*)d_in[0];
    const float* edge_attr  = (const float*)d_in[1];
    const float* Wnp = (const float*)d_in[2];
    const float* bnp = (const float*)d_in[3];
    const float* Wep = (const float*)d_in[4];
    const float* bep = (const float*)d_in[5];
    const float* Wg1 = (const float*)d_in[6];
    const float* as1 = (const float*)d_in[7];
    const float* ad1 = (const float*)d_in[8];
    const float* bg1 = (const float*)d_in[9];
    const float* Wg2 = (const float*)d_in[10];
    const float* as2 = (const float*)d_in[11];
    const float* ad2 = (const float*)d_in[12];
    const float* bg2 = (const float*)d_in[13];
    const float* Wo  = (const float*)d_in[14];
    const float* bo  = (const float*)d_in[15];
    const int*   ei  = (const int*)d_in[16];

    const int N = in_sizes[0] / 128;   // 50000
    const int E = in_sizes[16] / 2;    // 800000
    const int* src = ei;
    const int* dst = ei + E;
    const int nchunk = (N + 255) / 256;
    const int EN = E + N;

    typedef unsigned short u16;

    // ---- workspace layout (256B-aligned regions) ----
    char* base = (char*)d_ws;
    size_t off = 0;
    auto alloc = [&](size_t bytes) -> char* {
        char* p = base + off;
        off += (bytes + 255) & ~(size_t)255;
        return p;
    };
    u16* xhh  = (u16*)alloc((size_t)N * 256 * 2);          // fp16 xh [N x 256]
    u16* x3F  = (u16*)alloc((size_t)N * 256 * 2);          // fp16 x3 [N x 256]
    u16* R3   = (u16*)alloc((size_t)N * 512 * 2);          // x4H/x4L (fp16 hilo)
    u16* nefF = (u16*)alloc((size_t)N * 32 * 2);           // compact nef fp16
    float* a_src = (float*)alloc((size_t)N * 4 * 4);
    float* a_dst = (float*)alloc((size_t)N * 4 * 4);
    float* Wc    = (float*)alloc(144 * 256 * 4);           // composed front weights
    float* c1    = (float*)alloc(256 * 4);                 // composed front bias
    u16* PcH  = (u16*)alloc(160 * 256 * 2);
    u16* PcL  = (u16*)alloc(160 * 256 * 2);
    u16* Pg2H = (u16*)alloc(256 * 256 * 2);
    u16* Pg2L = (u16*)alloc(256 * 256 * 2);
    u16* PoH  = (u16*)alloc(256 * 256 * 2);
    u16* PoL  = (u16*)alloc(256 * 256 * 2);
    int* cnt       = (int*)alloc((size_t)N * 4);
    int* rowptr    = (int*)alloc((size_t)(N + 1) * 4);
    int* fillptr   = (int*)alloc((size_t)N * 4);
    int* chunk_sum = (int*)alloc((size_t)nchunk * 4);
    int* chunk_off = (int*)alloc((size_t)nchunk * 4);
    int* colv      = (int*)alloc((size_t)EN * 4);
    int* eid       = (int*)alloc((size_t)EN * 4);

    u16* x4H = R3;
    u16* x4L = R3 + (size_t)N * 256;

    float* out = (float*)d_out;
    dim3 ggrid((N + 127) / 128, 4);

    // ---- CSR build ----
    hipMemsetAsync(cnt, 0, (size_t)N * sizeof(int), stream);
    count_kernel<<<(E + 255) / 256, 256, 0, stream>>>(dst, cnt, E);
    scan1_kernel<<<nchunk, 256, 0, stream>>>(cnt, chunk_sum, N);
    scan2_kernel<<<1, 256, 0, stream>>>(chunk_sum, chunk_off, nchunk);
    scan3_kernel<<<nchunk, 256, 0, stream>>>(cnt, chunk_off, rowptr, fillptr, colv, eid, N);
    fill_kernel<<<(E + 255) / 256, 256, 0, stream>>>(src, dst, fillptr, colv, eid, E);

    // ---- nef (compact fp16); weight compose + packing ----
    nef_csr_kernel<<<(N + 3) / 4, 256, 0, stream>>>(edge_attr, rowptr, eid, nefF, N);
    compose_w1_kernel<<<145, 256, 0, stream>>>(Wnp, Wep, bnp, bep, Wg1, Wc, c1);
    {
        const int total = 160 * 256 + 256 * 256 + 256 * 256;
        pack3_w_kernel<<<(total + 255) / 256, 256, 0, stream>>>(
            Wc, PcH, PcL, Wg2, Pg2H, Pg2L, Wo, PoH, PoL);
    }

    // ---- GAT layer 1: composed GEMM (K=160; f32 nf direct + nef) -> agg ----
    mfma_gemm_kernel<5, 3, 2, true><<<ggrid, 256, 0, stream>>>(
        nefF, nullptr, node_feats, 160, PcH, PcL, c1, nullptr, xhh, nullptr,
        256, 0, N, as1, ad1, a_src, a_dst);
    gat_agg_csr_kernel<true><<<(N + 3) / 4, 256, 0, stream>>>(
        xhh, rowptr, colv, a_src, a_dst, bg1, x3F, nullptr, N);

    // ---- GAT layer 2 (fp16 A single) ----
    mfma_gemm_kernel<8, 1, 2, true><<<ggrid, 256, 0, stream>>>(
        x3F, nullptr, nullptr, 256, Pg2H, Pg2L, nullptr, nullptr, xhh, nullptr,
        256, 0, N, as2, ad2, a_src, a_dst);
    gat_agg_csr_kernel<false><<<(N + 3) / 4, 256, 0, stream>>>(
        xhh, rowptr, colv, a_src, a_dst, bg2, x4H, x4L, N);

    // ---- out = x4 @ Wo + bo -> d_out (f32), fp16 hilo A ----
    mfma_gemm_kernel<8, 0, 0, false><<<ggrid, 256, 0, stream>>>(
        x4H, x4L, nullptr, 256, PoH, PoL, bo, out, nullptr, nullptr,
        256, 0, N, nullptr, nullptr, nullptr, nullptr);
}

// Round 11
// 534.136 us; speedup vs baseline: 1.0540x; 1.0540x over previous
//
#include <hip/hip_runtime.h>
#include <hip/hip_bf16.h>

// GNN: node_proj + edge scatter_mean/proj -> concat -> GAT(512->4x64) -> ELU
//      -> GAT(256->4x64) -> ELU -> out_proj. ALL tensors float32 (per ref).
// R17: REVERT to R15 (best measured: 532us). R16's barrier-free full-panel
//      stage regressed (563us): 64KB LDS -> 2 blocks/CU = 8 waves/CU, too
//      few to hide A latency; the removed barriers were also providing
//      inter-wave overlap. Three GEMM structures (R10 prefetch, R14 fewer
//      MFMAs, R16 barrier-free) have now all failed to beat R15's
//      {preload-all-A + 1 barrier/kstep + 32KB dbuf B} -- remaining GEMM
//      time is structural latency of tiny-K GEMMs.
//      Agg floor: ~3.0 TB/s fabric random-gather ceiling, 7th measurement
//      (210MB @ ~70.5us x2). fp8 xh would breach absmax; no lever left.

#define HEADS 4

typedef __attribute__((ext_vector_type(8))) _Float16 f16x8;
typedef __attribute__((ext_vector_type(4))) float f32x4;
typedef __attribute__((ext_vector_type(4))) unsigned short u16x4;
typedef __attribute__((ext_vector_type(8))) unsigned short u16x8;

__device__ __forceinline__ unsigned short f2h(float v) {
    _Float16 h = (_Float16)v;                 // v_cvt_f16_f32, RN
    return __builtin_bit_cast(unsigned short, h);
}
__device__ __forceinline__ float h2f(unsigned short u) {
    return (float)__builtin_bit_cast(_Float16, u);
}
// fp16 hi/lo split: h + l reproduces v to ~22 mantissa bits
__device__ __forceinline__ void split_hilo16(float v, unsigned short& h, unsigned short& l) {
    h = f2h(v);
    l = f2h(v - h2f(h));
}
// async global->LDS, 16B per lane; LDS dest is wave-uniform base + lane*16
__device__ __forceinline__ void gl2lds16(const unsigned short* g, unsigned short* l) {
    __builtin_amdgcn_global_load_lds(
        (const __attribute__((address_space(1))) unsigned int*)g,
        (__attribute__((address_space(3))) unsigned int*)l,
        16, 0, 0);
}

// ============================ CSR construction =============================

__global__ __launch_bounds__(256) void count_kernel(
    const int* __restrict__ dst, int* __restrict__ cnt, int E)
{
    int e = blockIdx.x * 256 + threadIdx.x;
    if (e < E) atomicAdd(&cnt[dst[e]], 1);
}

__global__ __launch_bounds__(256) void scan1_kernel(
    const int* __restrict__ cnt, int* __restrict__ chunk_sum, int N)
{
    __shared__ int sd[256];
    int t = threadIdx.x;
    int n = blockIdx.x * 256 + t;
    sd[t] = (n < N) ? (cnt[n] + 1) : 0;
    __syncthreads();
    for (int o = 128; o > 0; o >>= 1) {
        if (t < o) sd[t] += sd[t + o];
        __syncthreads();
    }
    if (t == 0) chunk_sum[blockIdx.x] = sd[0];
}

// 1-block 256-thread scan over chunk sums
__global__ __launch_bounds__(256) void scan2_kernel(
    const int* __restrict__ chunk_sum, int* __restrict__ chunk_off, int nchunk)
{
    __shared__ int sd[256];
    __shared__ int carry;
    int t = threadIdx.x;
    if (t == 0) carry = 0;
    __syncthreads();
    for (int b = 0; b < nchunk; b += 256) {
        int i = b + t;
        int v = (i < nchunk) ? chunk_sum[i] : 0;
        sd[t] = v;
        __syncthreads();
        for (int o = 1; o < 256; o <<= 1) {
            int x = (t >= o) ? sd[t - o] : 0;
            __syncthreads();
            sd[t] += x;
            __syncthreads();
        }
        if (i < nchunk) chunk_off[i] = carry + sd[t] - v;
        __syncthreads();
        if (t == 0) carry += sd[255];
        __syncthreads();
    }
}

__global__ __launch_bounds__(256) void scan3_kernel(
    const int* __restrict__ cnt, const int* __restrict__ chunk_off,
    int* __restrict__ rowptr, int* __restrict__ fillptr,
    int* __restrict__ col, int* __restrict__ eid, int N)
{
    __shared__ int sd[256];
    int t = threadIdx.x;
    int n = blockIdx.x * 256 + t;
    int v = (n < N) ? (cnt[n] + 1) : 0;
    sd[t] = v;
    __syncthreads();
    for (int o = 1; o < 256; o <<= 1) {
        int x = (t >= o) ? sd[t - o] : 0;
        __syncthreads();
        sd[t] += x;
        __syncthreads();
    }
    if (n < N) {
        int incl = sd[t];
        int r = chunk_off[blockIdx.x] + incl - v;
        rowptr[n] = r;
        col[r] = n;        // self loop, first entry
        eid[r] = -1;
        fillptr[n] = r + 1;
        if (n == N - 1) rowptr[N] = chunk_off[blockIdx.x] + incl;
    }
}

__global__ __launch_bounds__(256) void fill_kernel(
    const int* __restrict__ src, const int* __restrict__ dst,
    int* __restrict__ fillptr, int* __restrict__ col, int* __restrict__ eid, int E)
{
    int e = blockIdx.x * 256 + threadIdx.x;
    if (e >= E) return;
    int d = dst[e];
    int p = atomicAdd(&fillptr[d], 1);
    col[p] = src[e];
    eid[p] = e;
}

// ====== edge_attr scatter-mean via CSR -> compact fp16 nef [N x 32] ========
// cols 0..15 = mean(edge_attr), 16..31 = zero (K padding for the GEMM).
__global__ __launch_bounds__(256) void nef_csr_kernel(
    const float* __restrict__ ea, const int* __restrict__ rowptr,
    const int* __restrict__ eid,
    unsigned short* __restrict__ nefF, int N)
{
    int n = blockIdx.x * 4 + (threadIdx.x >> 6);
    if (n >= N) return;
    int t = threadIdx.x & 63;
    int f = t & 15, g = t >> 4;
    int base = rowptr[n], end = rowptr[n + 1];
    int deg = end - base - 1;
    float acc = 0.0f;
    for (int j = base + 1 + g; j < end; j += 4) {
        int e = eid[j];
        acc += ea[(size_t)e * 16 + f];
    }
    acc += __shfl_down(acc, 32, 64);
    acc += __shfl_down(acc, 16, 64);
    if (t < 16) {
        float v = acc / fmaxf((float)deg, 1.0f);
        nefF[(size_t)n * 32 + t] = f2h(v);
    } else if (t < 32) {
        nefF[(size_t)n * 32 + t] = 0;
    }
}

// ====== compose front-end weights (f32, exact):
// Wc rows 0..127 = Wnp @ Wg1[0:256,:], rows 128..143 = Wep @ Wg1[256:512,:],
// c1[j] = bnp @ Wg1[0:256,j] + bep @ Wg1[256:512,j].
__global__ __launch_bounds__(256) void compose_w1_kernel(
    const float* __restrict__ Wnp, const float* __restrict__ Wep,
    const float* __restrict__ bnp, const float* __restrict__ bep,
    const float* __restrict__ Wg1,
    float* __restrict__ Wc, float* __restrict__ c1)
{
    int idx = blockIdx.x * 256 + threadIdx.x;
    if (idx >= 145 * 256) return;
    int i = idx >> 8, j = idx & 255;
    float s = 0.0f;
    if (i < 128) {
        for (int k = 0; k < 256; k++) s += Wnp[i * 256 + k] * Wg1[(size_t)k * 256 + j];
        Wc[i * 256 + j] = s;
    } else if (i < 144) {
        int ii = i - 128;
        for (int k = 0; k < 256; k++) s += Wep[ii * 256 + k] * Wg1[(size_t)(256 + k) * 256 + j];
        Wc[i * 256 + j] = s;
    } else {
        for (int k = 0; k < 256; k++)
            s += bnp[k] * Wg1[(size_t)k * 256 + j] + bep[k] * Wg1[(size_t)(256 + k) * 256 + j];
        c1[j] = s;
    }
}

// ==== pack 3 weight matrices [K x 256] -> B-fragment order, fp16 hi/lo ====
__device__ __forceinline__ void pack_one(
    const float* __restrict__ W, int K, int KP, int idx,
    unsigned short* __restrict__ Ph, unsigned short* __restrict__ Pl)
{
    int tile = idx >> 9, w = idx & 511, lane = w >> 3, j = w & 7;
    int nk = KP >> 5;
    int ctile = tile / nk, t = tile % nk;
    int k = t * 32 + ((lane >> 4) << 3) + j;
    int n = (ctile << 4) + (lane & 15);
    float v = (k < K) ? W[(size_t)k * 256 + n] : 0.0f;
    unsigned short h, l;
    split_hilo16(v, h, l);
    Ph[idx] = h;
    Pl[idx] = l;
}

__global__ __launch_bounds__(256) void pack3_w_kernel(
    const float* __restrict__ Wc,  unsigned short* __restrict__ PcH,  unsigned short* __restrict__ PcL,
    const float* __restrict__ Wg2, unsigned short* __restrict__ Pg2H, unsigned short* __restrict__ Pg2L,
    const float* __restrict__ Wo,  unsigned short* __restrict__ PoH,  unsigned short* __restrict__ PoL)
{
    const int S0 = 160 * 256;            // Wc: K=144, KP=160
    const int S1 = S0 + 256 * 256;       // Wg2
    const int S2 = S1 + 256 * 256;       // Wo
    int idx = blockIdx.x * 256 + threadIdx.x;
    if (idx < S0) {
        pack_one(Wc, 144, 160, idx, PcH, PcL);
    } else if (idx < S1) {
        pack_one(Wg2, 256, 256, idx - S0, Pg2H, Pg2L);
    } else if (idx < S2) {
        pack_one(Wo, 256, 256, idx - S1, PoH, PoL);
    }
}

// ===================== MFMA fp16 GEMM ======================================
// C[N x 256] = A[N x KP] @ W[KP x 256] (+bias). Block: 64 rows x 128 cols
// (grid.y=2), 4 waves (wave = 16 rows), 8 col-tiles. B panel (fp16 hi/lo)
// double-buffered in LDS via global_load_lds. ALL A fragments preloaded at
// kernel entry (independent, all in flight; first barrier pays latency once,
// later barriers have zero A exposure). AMODE: 0 = fp16 hilo A (3 MFMAs),
// 1 = fp16 single A (2 MFMAs), 3 = GEMM1-direct: ksteps 0..KSTEPS-2 read
// f32 from Af32 [N x 128] (cvt in-register, bit-identical to stored fp16),
// last kstep reads compact nef fp16 [N x 32]. OMODE: 0 = f32, 1 = fp16
// hilo, 2 = fp16. FUSE_ATT: per-row per-head dots of (acc+bias).
template <int KSTEPS, int AMODE, int OMODE, bool FUSE_ATT>
__global__ __launch_bounds__(256, 4) void mfma_gemm_kernel(
    const unsigned short* __restrict__ Ah, const unsigned short* __restrict__ Al,
    const float* __restrict__ Af32,
    int lda,
    const unsigned short* __restrict__ Ph, const unsigned short* __restrict__ Pl,
    const float* __restrict__ bias,
    float* __restrict__ Cf,
    unsigned short* __restrict__ Ch, unsigned short* __restrict__ Cl,
    int ldc, int col_off, int Nrows,
    const float* __restrict__ att_src, const float* __restrict__ att_dst,
    float* __restrict__ a_srcO, float* __restrict__ a_dstO)
{
    __shared__ unsigned short ldsB[2][2][8][512];   // [buf][hi/lo][ctile][elem]
    int tid = threadIdx.x;
    int wave = tid >> 6, lane = tid & 63;
    int quad = lane >> 4, m16 = lane & 15;
    int rowblk = blockIdx.x, colhalf = blockIdx.y;
    int ctile0 = colhalf * 8;

    int row = rowblk * 64 + wave * 16 + m16;
    bool rowok = row < Nrows;

    auto stage = [&](int t, int buf) {
        #pragma unroll
        for (int q = 0; q < 2; q++) {
            int c = wave * 2 + q;
            size_t gb = ((size_t)((ctile0 + c) * KSTEPS + t)) * 512 + lane * 8;
            gl2lds16(Ph + gb, &ldsB[buf][0][c][0]);
            gl2lds16(Pl + gb, &ldsB[buf][1][c][0]);
        }
    };

    // ---------- preload ALL A fragments (independent, all in flight) ------
    u16x8 aH[KSTEPS];                       // fp16 frags (AMODE 0/1; AMODE3: last)
    u16x8 aL[AMODE == 0 ? KSTEPS : 1];      // lo frags (AMODE 0 only)
    f32x4 aF[AMODE == 3 ? 2 * KSTEPS : 1];  // f32 pairs (AMODE 3, ksteps 0..KS-2)
    #pragma unroll
    for (int t = 0; t < KSTEPS; t++) {
        if (AMODE == 3) {
            if (t < KSTEPS - 1) {
                aF[2 * t] = (f32x4){};
                aF[2 * t + 1] = (f32x4){};
                if (rowok) {
                    const float* p = Af32 + (size_t)row * 128 + t * 32 + quad * 8;
                    aF[2 * t]     = *(const f32x4*)p;
                    aF[2 * t + 1] = *(const f32x4*)(p + 4);
                }
            } else {
                aH[t] = (u16x8){};
                if (rowok) aH[t] = *(const u16x8*)(Ah + (size_t)row * 32 + quad * 8);
            }
        } else {
            int k = t * 32 + quad * 8;
            aH[t] = (u16x8){};
            if (rowok) aH[t] = *(const u16x8*)(Ah + (size_t)row * lda + k);
            if (AMODE == 0) {
                aL[t] = (u16x8){};
                if (rowok) aL[t] = *(const u16x8*)(Al + (size_t)row * lda + k);
            }
        }
    }

    f32x4 acc[8] = {};
    stage(0, 0);
    __syncthreads();

    #pragma unroll
    for (int t = 0; t < KSTEPS; t++) {
        const int buf = t & 1;
        if (t + 1 < KSTEPS) stage(t + 1, buf ^ 1);

        // materialize this step's fp16 A operand (static index after unroll)
        f16x8 a_h, a_l;
        if (AMODE == 3 && t < KSTEPS - 1) {
            #pragma unroll
            for (int i = 0; i < 4; i++) {
                ((_Float16*)&a_h)[i]     = (_Float16)aF[2 * t][i];
                ((_Float16*)&a_h)[4 + i] = (_Float16)aF[2 * t + 1][i];
            }
        } else {
            a_h = __builtin_bit_cast(f16x8, aH[t]);
        }
        if (AMODE == 0) a_l = __builtin_bit_cast(f16x8, aL[t]);

        #pragma unroll
        for (int c = 0; c < 8; c++) {
            f16x8 b_h = __builtin_bit_cast(f16x8, *(const u16x8*)&ldsB[buf][0][c][lane * 8]);
            f16x8 b_l = __builtin_bit_cast(f16x8, *(const u16x8*)&ldsB[buf][1][c][lane * 8]);
            acc[c] = __builtin_amdgcn_mfma_f32_16x16x32_f16(a_h, b_h, acc[c], 0, 0, 0);
            if (AMODE == 0)
                acc[c] = __builtin_amdgcn_mfma_f32_16x16x32_f16(a_l, b_h, acc[c], 0, 0, 0);
            acc[c] = __builtin_amdgcn_mfma_f32_16x16x32_f16(a_h, b_l, acc[c], 0, 0, 0);
        }
        if (t + 1 < KSTEPS) __syncthreads();
    }

    // epilogue: D[row = quad*4 + r][col = m16] within each 16x16 tile
    #pragma unroll
    for (int c = 0; c < 8; c++) {
        int ocol = (ctile0 + c) * 16 + m16;
        float bv = bias ? bias[ocol] : 0.0f;
        #pragma unroll
        for (int r = 0; r < 4; r++) {
            int orow = rowblk * 64 + wave * 16 + quad * 4 + r;
            if (orow >= Nrows) continue;
            float v = acc[c][r] + bv;
            size_t oidx = (size_t)orow * ldc + col_off + ocol;
            if (OMODE == 1) {
                unsigned short h, l;
                split_hilo16(v, h, l);
                Ch[oidx] = h;
                Cl[oidx] = l;
            } else if (OMODE == 2) {
                Ch[oidx] = f2h(v);
            } else {
                Cf[oidx] = v;
            }
        }
    }

    if (FUSE_ATT) {
        float ps[4][2] = {}, pd[4][2] = {};
        #pragma unroll
        for (int c = 0; c < 8; c++) {
            int ocol = (ctile0 + c) * 16 + m16;
            float bv = bias ? bias[ocol] : 0.0f;
            float asv = att_src[ocol];
            float adv = att_dst[ocol];
            int hl = c >> 2;
            #pragma unroll
            for (int r = 0; r < 4; r++) {
                float v = acc[c][r] + bv;
                ps[r][hl] += v * asv;
                pd[r][hl] += v * adv;
            }
        }
        #pragma unroll
        for (int r = 0; r < 4; r++) {
            #pragma unroll
            for (int hl = 0; hl < 2; hl++) {
                float s = ps[r][hl], d = pd[r][hl];
                #pragma unroll
                for (int o = 8; o > 0; o >>= 1) {
                    s += __shfl_down(s, o, 64);
                    d += __shfl_down(d, o, 64);
                }
                if (m16 == 0) {
                    int orow = rowblk * 64 + wave * 16 + quad * 4 + r;
                    if (orow < Nrows) {
                        int gh = colhalf * 2 + hl;
                        a_srcO[orow * 4 + gh] = s;
                        a_dstO[orow * 4 + gh] = d;
                    }
                }
            }
        }
    }
}

// ===== CSR aggregation: wave-per-node; fused weight phase + weighted sum ===
// 4 nodes per 256-thread block; wave w owns node blockIdx*4+w.
// Phase 1 (fast path, deg<=128): lane-per-edge computes all 4 head weights
// into wave-private LDS + shuffle-reduced denominator (producer wave ==
// consumer wave, no barrier). Slow path (deg>128, ~never): inline weights.
// Phase 2: each lane covers 4 consecutive cols; masked unroll-4 gather.
// OUTF16: true -> single fp16 store (x3); false -> fp16 hilo (x4).
template <bool OUTF16>
__global__ __launch_bounds__(256) void gat_agg_csr_kernel(
    const unsigned short* __restrict__ xh,      // fp16 [N x 256]
    const int* __restrict__ rowptr, const int* __restrict__ col,
    const float* __restrict__ a_src, const float* __restrict__ a_dst,
    const float* __restrict__ bias,
    unsigned short* __restrict__ outA, unsigned short* __restrict__ outB, int N)
{
    __shared__ float wlds[4][128][HEADS];       // 8 KB, wave-private rows
    int t = threadIdx.x;
    int wv = t >> 6;
    int n = blockIdx.x * 4 + wv;
    if (n >= N) return;
    int c = t & 63;
    int h = c >> 4;
    int base = rowptr[n], end = rowptr[n + 1];
    int deg = end - base;                       // >= 1 (self loop)
    int e1 = end - 1;
    float4 ad = *(const float4*)&a_dst[n * 4];
    float adh = (h == 0) ? ad.x : (h == 1) ? ad.y : (h == 2) ? ad.z : ad.w;
    const unsigned short* xcol = xh + (c << 2);

    float4 acc = {0.0f, 0.0f, 0.0f, 0.0f};
    float den = 0.0f;

    if (deg <= 128) {
        // ---- phase 1: weights into LDS (lane-per-edge) + denominator ----
        float4 ds = {0.0f, 0.0f, 0.0f, 0.0f};
        for (int j = base + c; j < end; j += 64) {
            int s = col[j];
            float4 as4 = *(const float4*)&a_src[s * 4];
            float l0 = as4.x + ad.x, l1 = as4.y + ad.y;
            float l2 = as4.z + ad.z, l3 = as4.w + ad.w;
            l0 = fmaxf(l0, 0.2f * l0);
            l1 = fmaxf(l1, 0.2f * l1);
            l2 = fmaxf(l2, 0.2f * l2);
            l3 = fmaxf(l3, 0.2f * l3);
            float4 wv4 = {__expf(l0), __expf(l1), __expf(l2), __expf(l3)};
            *(float4*)&wlds[wv][j - base][0] = wv4;
            ds.x += wv4.x; ds.y += wv4.y; ds.z += wv4.z; ds.w += wv4.w;
        }
        #pragma unroll
        for (int o = 32; o > 0; o >>= 1) {
            ds.x += __shfl_down(ds.x, o, 64);
            ds.y += __shfl_down(ds.y, o, 64);
            ds.z += __shfl_down(ds.z, o, 64);
            ds.w += __shfl_down(ds.w, o, 64);
        }
        float d0 = __shfl(ds.x, 0, 64);
        float d1 = __shfl(ds.y, 0, 64);
        float d2 = __shfl(ds.z, 0, 64);
        float d3 = __shfl(ds.w, 0, 64);
        den = (h == 0) ? d0 : (h == 1) ? d1 : (h == 2) ? d2 : d3;

        // ---- phase 2: gather-accumulate, weights broadcast from LDS ----
        for (int j = base; j < end; j += 4) {
            int j1 = j + 1 < e1 ? j + 1 : e1;
            int j2 = j + 2 < e1 ? j + 2 : e1;
            int j3 = j + 3 < e1 ? j + 3 : e1;
            int s0 = col[j], s1 = col[j1], s2 = col[j2], s3 = col[j3];
            float w0 = wlds[wv][j - base][h];
            float w1 = (j + 1 < end) ? wlds[wv][j1 - base][h] : 0.0f;
            float w2 = (j + 2 < end) ? wlds[wv][j2 - base][h] : 0.0f;
            float w3 = (j + 3 < end) ? wlds[wv][j3 - base][h] : 0.0f;
            u16x4 x0 = *(const u16x4*)(xcol + (size_t)s0 * 256);
            u16x4 x1 = *(const u16x4*)(xcol + (size_t)s1 * 256);
            u16x4 x2 = *(const u16x4*)(xcol + (size_t)s2 * 256);
            u16x4 x3 = *(const u16x4*)(xcol + (size_t)s3 * 256);
            acc.x += w0 * h2f(x0[0]) + w1 * h2f(x1[0]) + w2 * h2f(x2[0]) + w3 * h2f(x3[0]);
            acc.y += w0 * h2f(x0[1]) + w1 * h2f(x1[1]) + w2 * h2f(x2[1]) + w3 * h2f(x3[1]);
            acc.z += w0 * h2f(x0[2]) + w1 * h2f(x1[2]) + w2 * h2f(x2[2]) + w3 * h2f(x3[2]);
            acc.w += w0 * h2f(x0[3]) + w1 * h2f(x1[3]) + w2 * h2f(x2[3]) + w3 * h2f(x3[3]);
        }
    } else {
        // ---- slow path (deg > 128, practically never): inline weights ----
        for (int j = base; j < end; j += 4) {
            int j1 = j + 1 < e1 ? j + 1 : e1;
            int j2 = j + 2 < e1 ? j + 2 : e1;
            int j3 = j + 3 < e1 ? j + 3 : e1;
            int s0 = col[j], s1 = col[j1], s2 = col[j2], s3 = col[j3];
            float l0 = a_src[s0 * 4 + h] + adh;
            float l1 = a_src[s1 * 4 + h] + adh;
            float l2 = a_src[s2 * 4 + h] + adh;
            float l3 = a_src[s3 * 4 + h] + adh;
            l0 = fmaxf(l0, 0.2f * l0);
            l1 = fmaxf(l1, 0.2f * l1);
            l2 = fmaxf(l2, 0.2f * l2);
            l3 = fmaxf(l3, 0.2f * l3);
            float w0 = __expf(l0);
            float w1 = (j + 1 < end) ? __expf(l1) : 0.0f;
            float w2 = (j + 2 < end) ? __expf(l2) : 0.0f;
            float w3 = (j + 3 < end) ? __expf(l3) : 0.0f;
            u16x4 x0 = *(const u16x4*)(xcol + (size_t)s0 * 256);
            u16x4 x1 = *(const u16x4*)(xcol + (size_t)s1 * 256);
            u16x4 x2 = *(const u16x4*)(xcol + (size_t)s2 * 256);
            u16x4 x3 = *(const u16x4*)(xcol + (size_t)s3 * 256);
            den += (w0 + w1) + (w2 + w3);
            acc.x += w0 * h2f(x0[0]) + w1 * h2f(x1[0]) + w2 * h2f(x2[0]) + w3 * h2f(x3[0]);
            acc.y += w0 * h2f(x0[1]) + w1 * h2f(x1[1]) + w2 * h2f(x2[1]) + w3 * h2f(x3[1]);
            acc.z += w0 * h2f(x0[2]) + w1 * h2f(x1[2]) + w2 * h2f(x2[2]) + w3 * h2f(x3[2]);
            acc.w += w0 * h2f(x0[3]) + w1 * h2f(x1[3]) + w2 * h2f(x2[3]) + w3 * h2f(x3[3]);
        }
    }

    float inv = 1.0f / den;
    float4 bv = *(const float4*)(bias + (c << 2));
    float o0 = acc.x * inv + bv.x;
    float o1 = acc.y * inv + bv.y;
    float o2 = acc.z * inv + bv.z;
    float o3 = acc.w * inv + bv.w;
    o0 = (o0 > 0.0f) ? o0 : (__expf(o0) - 1.0f);
    o1 = (o1 > 0.0f) ? o1 : (__expf(o1) - 1.0f);
    o2 = (o2 > 0.0f) ? o2 : (__expf(o2) - 1.0f);
    o3 = (o3 > 0.0f) ? o3 : (__expf(o3) - 1.0f);
    if (OUTF16) {
        u16x4 H;
        H[0] = f2h(o0); H[1] = f2h(o1); H[2] = f2h(o2); H[3] = f2h(o3);
        *(u16x4*)(&outA[(size_t)n * 256 + (c << 2)]) = H;
    } else {
        u16x4 H, L;
        split_hilo16(o0, ((unsigned short*)&H)[0], ((unsigned short*)&L)[0]);
        split_hilo16(o1, ((unsigned short*)&H)[1], ((unsigned short*)&L)[1]);
        split_hilo16(o2, ((unsigned short*)&H)[2], ((unsigned short*)&L)[2]);
        split_hilo16(o3, ((unsigned short*)&H)[3], ((unsigned short*)&L)[3]);
        *(u16x4*)(&outA[(size_t)n * 256 + (c << 2)]) = H;
        *(u16x4*)(&outB[(size_t)n * 256 + (c << 2)]) = L;
    }
}

// ===========================================================================

extern "C" void kernel_launch(void* const* d_in, const int* in_sizes, int n_in,
                              void* d_out, int out_size, void* d_ws, size_t ws_size,
                              hipStream_t stream)
{
    const float* node_feats = (const float*)d_in[0];
    const float* edge_attr  = (const float*)d_in[1];
    const float* Wnp = (const float*)d_in[2];
    const float* bnp = (const float*)d_in[3];
    const float* Wep = (const float*)d_in[4];
    const float* bep = (const float*)d_in[5];
    const float* Wg1 = (const float*)d_in[6];
    const float* as1 = (const float*)d_in[7];
    const float* ad1 = (const float*)d_in[8];
    const float* bg1 = (const float*)d_in[9];
    const float* Wg2 = (const float*)d_in[10];
    const float* as2 = (const float*)d_in[11];
    const float* ad2 = (const float*)d_in[12];
    const float* bg2 = (const float*)d_in[13];
    const float* Wo  = (const float*)d_in[14];
    const float* bo  = (const float*)d_in[15];
    const int*   ei  = (const int*)d_in[16];

    const int N = in_sizes[0] / 128;   // 50000
    const int E = in_sizes[16] / 2;    // 800000
    const int* src = ei;
    const int* dst = ei + E;
    const int nchunk = (N + 255) / 256;
    const int EN = E + N;

    typedef unsigned short u16;

    // ---- workspace layout (256B-aligned regions) ----
    char* base = (char*)d_ws;
    size_t off = 0;
    auto alloc = [&](size_t bytes) -> char* {
        char* p = base + off;
        off += (bytes + 255) & ~(size_t)255;
        return p;
    };
    u16* xhh  = (u16*)alloc((size_t)N * 256 * 2);          // fp16 xh [N x 256]
    u16* x3F  = (u16*)alloc((size_t)N * 256 * 2);          // fp16 x3 [N x 256]
    u16* R3   = (u16*)alloc((size_t)N * 512 * 2);          // x4H/x4L (fp16 hilo)
    u16* nefF = (u16*)alloc((size_t)N * 32 * 2);           // compact nef fp16
    float* a_src = (float*)alloc((size_t)N * 4 * 4);
    float* a_dst = (float*)alloc((size_t)N * 4 * 4);
    float* Wc    = (float*)alloc(144 * 256 * 4);           // composed front weights
    float* c1    = (float*)alloc(256 * 4);                 // composed front bias
    u16* PcH  = (u16*)alloc(160 * 256 * 2);
    u16* PcL  = (u16*)alloc(160 * 256 * 2);
    u16* Pg2H = (u16*)alloc(256 * 256 * 2);
    u16* Pg2L = (u16*)alloc(256 * 256 * 2);
    u16* PoH  = (u16*)alloc(256 * 256 * 2);
    u16* PoL  = (u16*)alloc(256 * 256 * 2);
    int* cnt       = (int*)alloc((size_t)N * 4);
    int* rowptr    = (int*)alloc((size_t)(N + 1) * 4);
    int* fillptr   = (int*)alloc((size_t)N * 4);
    int* chunk_sum = (int*)alloc((size_t)nchunk * 4);
    int* chunk_off = (int*)alloc((size_t)nchunk * 4);
    int* colv      = (int*)alloc((size_t)EN * 4);
    int* eid       = (int*)alloc((size_t)EN * 4);

    u16* x4H = R3;
    u16* x4L = R3 + (size_t)N * 256;

    float* out = (float*)d_out;
    dim3 ggrid((N + 63) / 64, 2);

    // ---- CSR build ----
    hipMemsetAsync(cnt, 0, (size_t)N * sizeof(int), stream);
    count_kernel<<<(E + 255) / 256, 256, 0, stream>>>(dst, cnt, E);
    scan1_kernel<<<nchunk, 256, 0, stream>>>(cnt, chunk_sum, N);
    scan2_kernel<<<1, 256, 0, stream>>>(chunk_sum, chunk_off, nchunk);
    scan3_kernel<<<nchunk, 256, 0, stream>>>(cnt, chunk_off, rowptr, fillptr, colv, eid, N);
    fill_kernel<<<(E + 255) / 256, 256, 0, stream>>>(src, dst, fillptr, colv, eid, E);

    // ---- nef (compact fp16); weight compose + packing ----
    nef_csr_kernel<<<(N + 3) / 4, 256, 0, stream>>>(edge_attr, rowptr, eid, nefF, N);
    compose_w1_kernel<<<145, 256, 0, stream>>>(Wnp, Wep, bnp, bep, Wg1, Wc, c1);
    {
        const int total = 160 * 256 + 256 * 256 + 256 * 256;
        pack3_w_kernel<<<(total + 255) / 256, 256, 0, stream>>>(
            Wc, PcH, PcL, Wg2, Pg2H, Pg2L, Wo, PoH, PoL);
    }

    // ---- GAT layer 1: composed GEMM (K=160; f32 nf direct + nef) -> agg ----
    mfma_gemm_kernel<5, 3, 2, true><<<ggrid, 256, 0, stream>>>(
        nefF, nullptr, node_feats, 160, PcH, PcL, c1, nullptr, xhh, nullptr,
        256, 0, N, as1, ad1, a_src, a_dst);
    gat_agg_csr_kernel<true><<<(N + 3) / 4, 256, 0, stream>>>(
        xhh, rowptr, colv, a_src, a_dst, bg1, x3F, nullptr, N);

    // ---- GAT layer 2 (fp16 A single, all-preload) ----
    mfma_gemm_kernel<8, 1, 2, true><<<ggrid, 256, 0, stream>>>(
        x3F, nullptr, nullptr, 256, Pg2H, Pg2L, nullptr, nullptr, xhh, nullptr,
        256, 0, N, as2, ad2, a_src, a_dst);
    gat_agg_csr_kernel<false><<<(N + 3) / 4, 256, 0, stream>>>(
        xhh, rowptr, colv, a_src, a_dst, bg2, x4H, x4L, N);

    // ---- out = x4 @ Wo + bo -> d_out (f32), fp16 hilo A, all-preload ----
    mfma_gemm_kernel<8, 0, 0, false><<<ggrid, 256, 0, stream>>>(
        x4H, x4L, nullptr, 256, PoH, PoL, bo, out, nullptr, nullptr,
        256, 0, N, nullptr, nullptr, nullptr, nullptr);
}